// Round 1
// baseline (1059.737 us; speedup 1.0000x reference)
//
#include <hip/hip_runtime.h>

typedef __attribute__((ext_vector_type(8))) __bf16 bf16x8;
typedef __attribute__((ext_vector_type(4))) float f32x4;

#define GLOAD_LDS16(g, l)                                                     \
  __builtin_amdgcn_global_load_lds(                                           \
      (const __attribute__((address_space(1))) void*)(g),                     \
      (__attribute__((address_space(3))) void*)(l), 16, 0, 0)

__device__ __forceinline__ unsigned short f32_to_bf16(float f) {
  unsigned int u = __builtin_bit_cast(unsigned int, f);
  u += 0x7FFFu + ((u >> 16) & 1u);
  return (unsigned short)(u >> 16);
}

// ---------------- f32 -> bf16 conversion (n4 = n/4 float4 groups) ----------
__global__ void conv_f32_bf16(const float* __restrict__ in,
                              unsigned short* __restrict__ out, int n4) {
  int stride = gridDim.x * blockDim.x;
  for (int i = blockIdx.x * blockDim.x + threadIdx.x; i < n4; i += stride) {
    float4 v = reinterpret_cast<const float4*>(in)[i];
    ushort4 o;
    o.x = f32_to_bf16(v.x);
    o.y = f32_to_bf16(v.y);
    o.z = f32_to_bf16(v.z);
    o.w = f32_to_bf16(v.w);
    reinterpret_cast<ushort4*>(out)[i] = o;
  }
}

// ---------------- FWHT along rows of 8192, scaled 1/sqrt(8192), bf16 out ---
__global__ void fwht_rows_bf16(const float* __restrict__ in,
                               unsigned short* __restrict__ out) {
  __shared__ float s[8192];
  const int tid = threadIdx.x;  // 256 threads
  const float* row = in + (size_t)blockIdx.x * 8192;
#pragma unroll
  for (int i = 0; i < 8; ++i)
    reinterpret_cast<float4*>(s)[tid + i * 256] =
        reinterpret_cast<const float4*>(row)[tid + i * 256];
  for (int h = 1; h < 8192; h <<= 1) {
    __syncthreads();
#pragma unroll
    for (int it = 0; it < 16; ++it) {
      int i = tid + it * 256;  // butterfly index, 4096 total
      int j = ((i & ~(h - 1)) << 1) | (i & (h - 1));
      float a = s[j], b = s[j + h];
      s[j] = a + b;
      s[j + h] = a - b;
    }
  }
  __syncthreads();
  const float scale = 0.011048543456039806f;  // 1/sqrt(8192)
  unsigned short* orow = out + (size_t)blockIdx.x * 8192;
#pragma unroll
  for (int i = 0; i < 8; ++i) {
    float4 v = reinterpret_cast<const float4*>(s)[tid + i * 256];
    ushort4 o;
    o.x = f32_to_bf16(v.x * scale);
    o.y = f32_to_bf16(v.y * scale);
    o.z = f32_to_bf16(v.z * scale);
    o.w = f32_to_bf16(v.w * scale);
    reinterpret_cast<ushort4*>(orow)[tid + i * 256] = o;
  }
}

// ---------------- dual-B GEMM + silu gate: H = silu(A*B1^T) .* (A*B3^T) ----
// A: M x K bf16 row-major; B1,B3: N x K bf16 row-major; Hout: M x N bf16.
__launch_bounds__(256, 2)
__global__ void gemm_dual_silu(const unsigned short* __restrict__ A,
                               const unsigned short* __restrict__ B1,
                               const unsigned short* __restrict__ B3,
                               unsigned short* __restrict__ Hout,
                               int M, int N, int K) {
  __shared__ __align__(16) unsigned short sA[128 * 32];
  __shared__ __align__(16) unsigned short sB1[128 * 32];
  __shared__ __align__(16) unsigned short sB3[128 * 32];

  const int tid = threadIdx.x;
  const int lane = tid & 63;
  const int wid = tid >> 6;
  const int wr = wid >> 1, wc = wid & 1;

  const int bm = blockIdx.y * 128;
  const int bn = blockIdx.x * 128;

  // staging: wave wid, sub-issue q covers rows [wid*32+q*16, +16), lane
  // (lane>>2) row within that, (lane&3)*8 bf16 col offset.
  const int srow = (wid << 5) + (lane >> 2);
  const int scol = (lane & 3) << 3;

  const unsigned short* gA = A + (size_t)(bm + srow) * K + scol;
  const unsigned short* gB1 = B1 + (size_t)(bn + srow) * K + scol;
  const unsigned short* gB3 = B3 + (size_t)(bn + srow) * K + scol;

  f32x4 accg[4][4], accl[4][4];
#pragma unroll
  for (int m = 0; m < 4; ++m)
#pragma unroll
    for (int n = 0; n < 4; ++n) {
      accg[m][n] = (f32x4)0.0f;
      accl[m][n] = (f32x4)0.0f;
    }

  const int fr = lane & 15;
  const int fk = (lane >> 4) << 3;

  for (int kt = 0; kt < K; kt += 32) {
    __syncthreads();
#pragma unroll
    for (int q = 0; q < 2; ++q) {
      const size_t go = (size_t)q * 16 * K + kt;
      const int lo = wid * 1024 + q * 512;  // ushort units
      GLOAD_LDS16(gA + go, sA + lo);
      GLOAD_LDS16(gB1 + go, sB1 + lo);
      GLOAD_LDS16(gB3 + go, sB3 + lo);
    }
    asm volatile("s_waitcnt vmcnt(0)" ::: "memory");
    __syncthreads();

    bf16x8 aF[4], b1F[4], b3F[4];
#pragma unroll
    for (int m = 0; m < 4; ++m)
      aF[m] = *reinterpret_cast<const bf16x8*>(
          &sA[(wr * 64 + m * 16 + fr) * 32 + fk]);
#pragma unroll
    for (int n = 0; n < 4; ++n) {
      b1F[n] = *reinterpret_cast<const bf16x8*>(
          &sB1[(wc * 64 + n * 16 + fr) * 32 + fk]);
      b3F[n] = *reinterpret_cast<const bf16x8*>(
          &sB3[(wc * 64 + n * 16 + fr) * 32 + fk]);
    }
#pragma unroll
    for (int m = 0; m < 4; ++m)
#pragma unroll
      for (int n = 0; n < 4; ++n) {
        accg[m][n] = __builtin_amdgcn_mfma_f32_16x16x32_bf16(
            aF[m], b1F[n], accg[m][n], 0, 0, 0);
        accl[m][n] = __builtin_amdgcn_mfma_f32_16x16x32_bf16(
            aF[m], b3F[n], accl[m][n], 0, 0, 0);
      }
  }

  // epilogue: h = silu(g) * l -> bf16
  const int er = (lane >> 4) << 2;  // 0,4,8,12
  const int ec = lane & 15;
#pragma unroll
  for (int m = 0; m < 4; ++m)
#pragma unroll
    for (int n = 0; n < 4; ++n)
#pragma unroll
      for (int r = 0; r < 4; ++r) {
        float g = accg[m][n][r];
        float li = accl[m][n][r];
        float h = (g / (1.0f + __expf(-g))) * li;
        size_t rowi = (size_t)(bm + wr * 64 + m * 16 + er + r);
        size_t coli = (size_t)(bn + wc * 64 + n * 16 + ec);
        Hout[rowi * N + coli] = f32_to_bf16(h);
      }
}

// ---------------- GEMM: C(f32) = A(bf16) * Bt(bf16)^T ----------------------
__launch_bounds__(256, 2)
__global__ void gemm_bt_f32(const unsigned short* __restrict__ A,
                            const unsigned short* __restrict__ Bt,
                            float* __restrict__ C, int M, int N, int K) {
  __shared__ __align__(16) unsigned short sA[128 * 32];
  __shared__ __align__(16) unsigned short sB[128 * 32];

  const int tid = threadIdx.x;
  const int lane = tid & 63;
  const int wid = tid >> 6;
  const int wr = wid >> 1, wc = wid & 1;

  const int bm = blockIdx.y * 128;
  const int bn = blockIdx.x * 128;

  const int srow = (wid << 5) + (lane >> 2);
  const int scol = (lane & 3) << 3;

  const unsigned short* gA = A + (size_t)(bm + srow) * K + scol;
  const unsigned short* gB = Bt + (size_t)(bn + srow) * K + scol;

  f32x4 acc[4][4];
#pragma unroll
  for (int m = 0; m < 4; ++m)
#pragma unroll
    for (int n = 0; n < 4; ++n) acc[m][n] = (f32x4)0.0f;

  const int fr = lane & 15;
  const int fk = (lane >> 4) << 3;

  for (int kt = 0; kt < K; kt += 32) {
    __syncthreads();
#pragma unroll
    for (int q = 0; q < 2; ++q) {
      const size_t go = (size_t)q * 16 * K + kt;
      const int lo = wid * 1024 + q * 512;
      GLOAD_LDS16(gA + go, sA + lo);
      GLOAD_LDS16(gB + go, sB + lo);
    }
    asm volatile("s_waitcnt vmcnt(0)" ::: "memory");
    __syncthreads();

    bf16x8 aF[4], bF[4];
#pragma unroll
    for (int m = 0; m < 4; ++m)
      aF[m] = *reinterpret_cast<const bf16x8*>(
          &sA[(wr * 64 + m * 16 + fr) * 32 + fk]);
#pragma unroll
    for (int n = 0; n < 4; ++n)
      bF[n] = *reinterpret_cast<const bf16x8*>(
          &sB[(wc * 64 + n * 16 + fr) * 32 + fk]);
#pragma unroll
    for (int m = 0; m < 4; ++m)
#pragma unroll
      for (int n = 0; n < 4; ++n)
        acc[m][n] = __builtin_amdgcn_mfma_f32_16x16x32_bf16(
            aF[m], bF[n], acc[m][n], 0, 0, 0);
  }

  const int er = (lane >> 4) << 2;
  const int ec = lane & 15;
#pragma unroll
  for (int m = 0; m < 4; ++m)
#pragma unroll
    for (int n = 0; n < 4; ++n)
#pragma unroll
      for (int r = 0; r < 4; ++r) {
        size_t rowi = (size_t)(bm + wr * 64 + m * 16 + er + r);
        size_t coli = (size_t)(bn + wc * 64 + n * 16 + ec);
        C[rowi * N + coli] = acc[m][n][r];
      }
}

extern "C" void kernel_launch(void* const* d_in, const int* in_sizes, int n_in,
                              void* d_out, int out_size, void* d_ws,
                              size_t ws_size, hipStream_t stream) {
  const float* x = (const float*)d_in[0];    // (4,2048,2048)
  const float* W1 = (const float*)d_in[1];   // (8192,2048)
  const float* W2 = (const float*)d_in[2];   // (2048,8192)
  const float* W3 = (const float*)d_in[3];   // (8192,2048)
  float* out = (float*)d_out;

  const int M = 8192;   // B*S
  const int D = 2048;
  const int H = 8192;
  const size_t NE = (size_t)16777216;  // elements in each of x,W1,W2,W3

  unsigned short* xb = (unsigned short*)d_ws;
  unsigned short* w1b = xb + NE;
  unsigned short* w3b = w1b + NE;
  unsigned short* w2f = w3b + NE;
  unsigned short* hid = w2f + NE;  // M x H bf16 = 134 MB

  conv_f32_bf16<<<2048, 256, 0, stream>>>(x, xb, (int)(NE / 4));
  conv_f32_bf16<<<2048, 256, 0, stream>>>(W1, w1b, (int)(NE / 4));
  conv_f32_bf16<<<2048, 256, 0, stream>>>(W3, w3b, (int)(NE / 4));
  fwht_rows_bf16<<<2048, 256, 0, stream>>>(W2, w2f);

  gemm_dual_silu<<<dim3(H / 128, M / 128), 256, 0, stream>>>(xb, w1b, w3b, hid,
                                                             M, H, D);
  gemm_bt_f32<<<dim3(D / 128, M / 128), 256, 0, stream>>>(hid, w2f, out, M, D,
                                                          H);
}

// Round 2
// 952.910 us; speedup vs baseline: 1.1121x; 1.1121x over previous
//
#include <hip/hip_runtime.h>

typedef __attribute__((ext_vector_type(8))) __bf16 bf16x8;
typedef __attribute__((ext_vector_type(4))) float f32x4;

#define GLOAD_LDS16(g, l)                                                     \
  __builtin_amdgcn_global_load_lds(                                           \
      (const __attribute__((address_space(1))) void*)(g),                     \
      (__attribute__((address_space(3))) void*)(l), 16, 0, 0)

#define BAR() __builtin_amdgcn_s_barrier()
#define LGKM0()                                                               \
  do {                                                                        \
    asm volatile("s_waitcnt lgkmcnt(0)" ::: "memory");                        \
    __builtin_amdgcn_sched_barrier(0);                                        \
  } while (0)
#define VMCNT6() asm volatile("s_waitcnt vmcnt(6)" ::: "memory")
#define VMCNT0() asm volatile("s_waitcnt vmcnt(0)" ::: "memory")
#define PRIO1() __builtin_amdgcn_s_setprio(1)
#define PRIO0() __builtin_amdgcn_s_setprio(0)

__device__ __forceinline__ unsigned short f32_to_bf16(float f) {
  unsigned int u = __builtin_bit_cast(unsigned int, f);
  u += 0x7FFFu + ((u >> 16) & 1u);
  return (unsigned short)(u >> 16);
}

// Stage a 128-row half-tile (rows [tileRow0+halfRow0, +128), k cols
// [kt, kt+64)) into LDS with the st_8x16-style XOR swizzle realized by
// pre-swizzling the per-lane GLOBAL source (LDS dest stays linear).
// 2 x global_load_lds_dwordx4 per wave. ldsTile = tile base (ushort*).
__device__ __forceinline__ void stage_half(const unsigned short* g,
                                           int tileRow0, int halfRow0, int kt,
                                           int Kelems, unsigned short* ldsTile,
                                           int wid, int lane) {
  // physical row within issue = wid*8 + lane/8 ; physical 16B slot = lane%8
  // logical col byte = physcol ^ ((row&7)<<4) ; row&7 == lane>>3
  const int swzcol = (((lane & 7) ^ (lane >> 3)) << 4);  // bytes
  const int r0 = tileRow0 + halfRow0 + (wid << 3) + (lane >> 3);
  const char* g0 =
      (const char*)g + ((size_t)r0 * Kelems + kt) * 2 + swzcol;
  unsigned short* l0 = ldsTile + halfRow0 * 64 + (wid << 9);  // wid*1024 B
  GLOAD_LDS16(g0, l0);
  const char* g1 = g0 + (size_t)64 * Kelems * 2;
  GLOAD_LDS16(g1, l0 + 64 * 64);
}

// Read one MFMA A/B fragment (16x16x32, bf16x8/lane) from the swizzled tile.
__device__ __forceinline__ bf16x8 lds_frag(const unsigned short* ldsTile,
                                           int row16, int ksub, int lane) {
  const int r = row16 + (lane & 15);
  const int cb = (ksub << 6) + ((lane >> 4) << 4);       // logical byte col
  const int off = (r << 7) + (cb ^ ((r & 7) << 4));      // physical byte
  return *reinterpret_cast<const bf16x8*>((const char*)ldsTile + off);
}

// ---------------- f32 -> bf16 conversion ----------------------------------
__global__ void conv_f32_bf16(const float* __restrict__ in,
                              unsigned short* __restrict__ out, int n4) {
  int stride = gridDim.x * blockDim.x;
  for (int i = blockIdx.x * blockDim.x + threadIdx.x; i < n4; i += stride) {
    float4 v = reinterpret_cast<const float4*>(in)[i];
    ushort4 o;
    o.x = f32_to_bf16(v.x);
    o.y = f32_to_bf16(v.y);
    o.z = f32_to_bf16(v.z);
    o.w = f32_to_bf16(v.w);
    reinterpret_cast<ushort4*>(out)[i] = o;
  }
}

// ---------------- FWHT rows of 8192, * 1/sqrt(8192), bf16 out --------------
__global__ void fwht_rows_bf16(const float* __restrict__ in,
                               unsigned short* __restrict__ out) {
  __shared__ float s[8192];
  const int tid = threadIdx.x;  // 256 threads
  const float* row = in + (size_t)blockIdx.x * 8192;
#pragma unroll
  for (int i = 0; i < 8; ++i)
    reinterpret_cast<float4*>(s)[tid + i * 256] =
        reinterpret_cast<const float4*>(row)[tid + i * 256];
  for (int h = 1; h < 8192; h <<= 1) {
    __syncthreads();
#pragma unroll
    for (int it = 0; it < 16; ++it) {
      int i = tid + it * 256;
      int j = ((i & ~(h - 1)) << 1) | (i & (h - 1));
      float a = s[j], b = s[j + h];
      s[j] = a + b;
      s[j + h] = a - b;
    }
  }
  __syncthreads();
  const float scale = 0.011048543456039806f;  // 1/sqrt(8192)
  unsigned short* orow = out + (size_t)blockIdx.x * 8192;
#pragma unroll
  for (int i = 0; i < 8; ++i) {
    float4 v = reinterpret_cast<const float4*>(s)[tid + i * 256];
    ushort4 o;
    o.x = f32_to_bf16(v.x * scale);
    o.y = f32_to_bf16(v.y * scale);
    o.z = f32_to_bf16(v.z * scale);
    o.w = f32_to_bf16(v.w * scale);
    reinterpret_cast<ushort4*>(orow)[tid + i * 256] = o;
  }
}

// ======================= GEMM1: dual-B + silu fuse =========================
// H[m][n] = silu(A·B1^T) * (A·B3^T), tile 256x128, BK=64, 8 waves (4M x 2N),
// per-wave 64x64. 4 phases/K-tile: (G,n01)(G,n23)(L,n23)(L,n01).
// Stage stream per tile u: [A0,A1,B1,B3](u) ; B3(t+1)@ph0, A0/A1/B1(t+2)@ph1-3.
__launch_bounds__(512, 2)
__global__ void gemm1_dual_silu(const unsigned short* __restrict__ A,
                                const unsigned short* __restrict__ B1p,
                                const unsigned short* __restrict__ B3p,
                                unsigned short* __restrict__ Hout,
                                int M, int N, int K) {
  __shared__ __align__(16) unsigned short sA[2][256 * 64];
  __shared__ __align__(16) unsigned short sB1[2][128 * 64];
  __shared__ __align__(16) unsigned short sB3[2][128 * 64];

  const int tid = threadIdx.x, lane = tid & 63, wid = tid >> 6;
  const int wr = wid >> 1, wc = wid & 1;

  const int nby = M >> 8;             // 32
  const int nwg = gridDim.x;          // (N/128)*(M/256), %8==0
  const int cpx = nwg >> 3;
  const int swz = ((int)blockIdx.x & 7) * cpx + ((int)blockIdx.x >> 3);
  const int bm = (swz % nby) << 8;    // column-major: chunk shares B panels
  const int bn = (swz / nby) << 7;
  const int NT = K >> 6;

  // prologue: [A0,A1,B1,B3](0), [A0,A1,B1](1) = 14 issues; retire tile0.
  stage_half(A, bm, 0, 0, K, sA[0], wid, lane);
  stage_half(A, bm, 128, 0, K, sA[0], wid, lane);
  stage_half(B1p, bn, 0, 0, K, sB1[0], wid, lane);
  stage_half(B3p, bn, 0, 0, K, sB3[0], wid, lane);
  stage_half(A, bm, 0, 64, K, sA[1], wid, lane);
  stage_half(A, bm, 128, 64, K, sA[1], wid, lane);
  stage_half(B1p, bn, 0, 64, K, sB1[1], wid, lane);
  VMCNT6();
  BAR();

  f32x4 accG[4][4], accL[4][4];
#pragma unroll
  for (int m = 0; m < 4; ++m)
#pragma unroll
    for (int n = 0; n < 4; ++n) {
      accG[m][n] = (f32x4)0.0f;
      accL[m][n] = (f32x4)0.0f;
    }
  bf16x8 ra[4][2], rb1[4][2], rb3[4][2];

  for (int t = 0; t < NT; ++t) {
    const int bi = t & 1;
    const unsigned short* a = sA[bi];
    const unsigned short* b1 = sB1[bi];
    const unsigned short* b3 = sB3[bi];
    const int kt1 = (t + 1) << 6, kt2 = (t + 2) << 6;

    // ---- ph0: read A(all m) + B1 n0,1 ; stage B3(t+1) ; MFMA G x n0,1
#pragma unroll
    for (int m = 0; m < 4; ++m)
#pragma unroll
      for (int ks = 0; ks < 2; ++ks)
        ra[m][ks] = lds_frag(a, wr * 64 + m * 16, ks, lane);
#pragma unroll
    for (int n = 0; n < 2; ++n)
#pragma unroll
      for (int ks = 0; ks < 2; ++ks)
        rb1[n][ks] = lds_frag(b1, wc * 64 + n * 16, ks, lane);
    if (t + 1 < NT) stage_half(B3p, bn, 0, kt1, K, sB3[bi ^ 1], wid, lane);
    BAR();
    LGKM0();
    PRIO1();
#pragma unroll
    for (int m = 0; m < 4; ++m)
#pragma unroll
      for (int n = 0; n < 2; ++n)
#pragma unroll
        for (int ks = 0; ks < 2; ++ks)
          accG[m][n] = __builtin_amdgcn_mfma_f32_16x16x32_bf16(
              ra[m][ks], rb1[n][ks], accG[m][n], 0, 0, 0);
    PRIO0();
    BAR();

    // ---- ph1: read B1 n2,3 ; stage A0(t+2) ; MFMA G x n2,3
#pragma unroll
    for (int n = 2; n < 4; ++n)
#pragma unroll
      for (int ks = 0; ks < 2; ++ks)
        rb1[n][ks] = lds_frag(b1, wc * 64 + n * 16, ks, lane);
    if (t + 2 < NT) stage_half(A, bm, 0, kt2, K, sA[bi], wid, lane);
    BAR();
    LGKM0();
    PRIO1();
#pragma unroll
    for (int m = 0; m < 4; ++m)
#pragma unroll
      for (int n = 2; n < 4; ++n)
#pragma unroll
        for (int ks = 0; ks < 2; ++ks)
          accG[m][n] = __builtin_amdgcn_mfma_f32_16x16x32_bf16(
              ra[m][ks], rb1[n][ks], accG[m][n], 0, 0, 0);
    PRIO0();
    BAR();

    // ---- ph2: read B3 n2,3 ; stage A1(t+2) ; MFMA L x n2,3
#pragma unroll
    for (int n = 2; n < 4; ++n)
#pragma unroll
      for (int ks = 0; ks < 2; ++ks)
        rb3[n][ks] = lds_frag(b3, wc * 64 + n * 16, ks, lane);
    if (t + 2 < NT) stage_half(A, bm, 128, kt2, K, sA[bi], wid, lane);
    BAR();
    LGKM0();
    PRIO1();
#pragma unroll
    for (int m = 0; m < 4; ++m)
#pragma unroll
      for (int n = 2; n < 4; ++n)
#pragma unroll
        for (int ks = 0; ks < 2; ++ks)
          accL[m][n] = __builtin_amdgcn_mfma_f32_16x16x32_bf16(
              ra[m][ks], rb3[n][ks], accL[m][n], 0, 0, 0);
    PRIO0();
    BAR();

    // ---- ph3: read B3 n0,1 ; stage B1(t+2) ; MFMA L x n0,1 ; vmcnt
#pragma unroll
    for (int n = 0; n < 2; ++n)
#pragma unroll
      for (int ks = 0; ks < 2; ++ks)
        rb3[n][ks] = lds_frag(b3, wc * 64 + n * 16, ks, lane);
    if (t + 2 < NT) stage_half(B1p, bn, 0, kt2, K, sB1[bi], wid, lane);
    BAR();
    LGKM0();
    PRIO1();
#pragma unroll
    for (int m = 0; m < 4; ++m)
#pragma unroll
      for (int n = 0; n < 2; ++n)
#pragma unroll
        for (int ks = 0; ks < 2; ++ks)
          accL[m][n] = __builtin_amdgcn_mfma_f32_16x16x32_bf16(
              ra[m][ks], rb3[n][ks], accL[m][n], 0, 0, 0);
    PRIO0();
    if (t < NT - 2) VMCNT6(); else VMCNT0();
    BAR();
  }

  // epilogue: h = silu(g)*l -> bf16
  const int er = (lane >> 4) << 2;
  const int ec = lane & 15;
#pragma unroll
  for (int m = 0; m < 4; ++m)
#pragma unroll
    for (int n = 0; n < 4; ++n)
#pragma unroll
      for (int r = 0; r < 4; ++r) {
        float g = accG[m][n][r];
        float li = accL[m][n][r];
        float h = (g / (1.0f + __expf(-g))) * li;
        size_t row = (size_t)(bm + wr * 64 + m * 16 + er + r);
        size_t col = (size_t)(bn + wc * 64 + n * 16 + ec);
        Hout[row * N + col] = f32_to_bf16(h);
      }
}

// ======================= GEMM2: C(f32) = A · Bt^T ==========================
// tile 256x256, BK=64, 8 waves (2M x 4N), per-wave 128x64.
// Phases: (mh0,nh0)(mh0,nh1)(mh1,nh1)(mh1,nh0).
// Stage stream per tile u: [B0,B1,A0,A1](u); A1(t+1)@ph0, B0/B1/A0(t+2)@ph1-3.
__launch_bounds__(512, 2)
__global__ void gemm2_8ph(const unsigned short* __restrict__ A,
                          const unsigned short* __restrict__ Bt,
                          float* __restrict__ C, int M, int N, int K) {
  __shared__ __align__(16) unsigned short sA[2][256 * 64];
  __shared__ __align__(16) unsigned short sB[2][256 * 64];

  const int tid = threadIdx.x, lane = tid & 63, wid = tid >> 6;
  const int wr = wid >> 2, wc = wid & 3;

  const int nbx = N >> 8;             // 8
  const int nwg = gridDim.x;
  const int cpx = nwg >> 3;
  const int swz = ((int)blockIdx.x & 7) * cpx + ((int)blockIdx.x >> 3);
  const int bm = (swz / nbx) << 8;    // row-major: chunk shares A panels
  const int bn = (swz % nbx) << 8;
  const int NT = K >> 6;

  stage_half(Bt, bn, 0, 0, K, sB[0], wid, lane);
  stage_half(Bt, bn, 128, 0, K, sB[0], wid, lane);
  stage_half(A, bm, 0, 0, K, sA[0], wid, lane);
  stage_half(A, bm, 128, 0, K, sA[0], wid, lane);
  stage_half(Bt, bn, 0, 64, K, sB[1], wid, lane);
  stage_half(Bt, bn, 128, 64, K, sB[1], wid, lane);
  stage_half(A, bm, 0, 64, K, sA[1], wid, lane);
  VMCNT6();
  BAR();

  f32x4 acc[8][4];
#pragma unroll
  for (int m = 0; m < 8; ++m)
#pragma unroll
    for (int n = 0; n < 4; ++n) acc[m][n] = (f32x4)0.0f;
  bf16x8 ra[4][2], rb[4][2];

  for (int t = 0; t < NT; ++t) {
    const int bi = t & 1;
    const unsigned short* a = sA[bi];
    const unsigned short* b = sB[bi];
    const int kt1 = (t + 1) << 6, kt2 = (t + 2) << 6;

    // ---- ph0: read A mh0 + B nh0 ; stage A1(t+1) ; MFMA (mh0,nh0)
#pragma unroll
    for (int m = 0; m < 4; ++m)
#pragma unroll
      for (int ks = 0; ks < 2; ++ks)
        ra[m][ks] = lds_frag(a, wr * 128 + m * 16, ks, lane);
#pragma unroll
    for (int n = 0; n < 2; ++n)
#pragma unroll
      for (int ks = 0; ks < 2; ++ks)
        rb[n][ks] = lds_frag(b, wc * 64 + n * 16, ks, lane);
    if (t + 1 < NT) stage_half(A, bm, 128, kt1, K, sA[bi ^ 1], wid, lane);
    BAR();
    LGKM0();
    PRIO1();
#pragma unroll
    for (int m = 0; m < 4; ++m)
#pragma unroll
      for (int n = 0; n < 2; ++n)
#pragma unroll
        for (int ks = 0; ks < 2; ++ks)
          acc[m][n] = __builtin_amdgcn_mfma_f32_16x16x32_bf16(
              ra[m][ks], rb[n][ks], acc[m][n], 0, 0, 0);
    PRIO0();
    BAR();

    // ---- ph1: read B nh1 ; stage B0(t+2) ; MFMA (mh0,nh1)
#pragma unroll
    for (int n = 2; n < 4; ++n)
#pragma unroll
      for (int ks = 0; ks < 2; ++ks)
        rb[n][ks] = lds_frag(b, wc * 64 + n * 16, ks, lane);
    if (t + 2 < NT) stage_half(Bt, bn, 0, kt2, K, sB[bi], wid, lane);
    BAR();
    LGKM0();
    PRIO1();
#pragma unroll
    for (int m = 0; m < 4; ++m)
#pragma unroll
      for (int n = 2; n < 4; ++n)
#pragma unroll
        for (int ks = 0; ks < 2; ++ks)
          acc[m][n] = __builtin_amdgcn_mfma_f32_16x16x32_bf16(
              ra[m][ks], rb[n][ks], acc[m][n], 0, 0, 0);
    PRIO0();
    BAR();

    // ---- ph2: read A mh1 ; stage B1(t+2) ; MFMA (mh1,nh1)
#pragma unroll
    for (int m = 0; m < 4; ++m)
#pragma unroll
      for (int ks = 0; ks < 2; ++ks)
        ra[m][ks] = lds_frag(a, wr * 128 + 64 + m * 16, ks, lane);
    if (t + 2 < NT) stage_half(Bt, bn, 128, kt2, K, sB[bi], wid, lane);
    BAR();
    LGKM0();
    PRIO1();
#pragma unroll
    for (int m = 0; m < 4; ++m)
#pragma unroll
      for (int n = 2; n < 4; ++n)
#pragma unroll
        for (int ks = 0; ks < 2; ++ks)
          acc[4 + m][n] = __builtin_amdgcn_mfma_f32_16x16x32_bf16(
              ra[m][ks], rb[n][ks], acc[4 + m][n], 0, 0, 0);
    PRIO0();
    BAR();

    // ---- ph3: stage A0(t+2) ; MFMA (mh1,nh0) ; vmcnt
    if (t + 2 < NT) stage_half(A, bm, 0, kt2, K, sA[bi], wid, lane);
    BAR();
    LGKM0();
    PRIO1();
#pragma unroll
    for (int m = 0; m < 4; ++m)
#pragma unroll
      for (int n = 0; n < 2; ++n)
#pragma unroll
        for (int ks = 0; ks < 2; ++ks)
          acc[4 + m][n] = __builtin_amdgcn_mfma_f32_16x16x32_bf16(
              ra[m][ks], rb[n][ks], acc[4 + m][n], 0, 0, 0);
    PRIO0();
    if (t < NT - 2) VMCNT6(); else VMCNT0();
    BAR();
  }

  const int er = (lane >> 4) << 2;
  const int ec = lane & 15;
#pragma unroll
  for (int mi = 0; mi < 8; ++mi)
#pragma unroll
    for (int n = 0; n < 4; ++n)
#pragma unroll
      for (int r = 0; r < 4; ++r) {
        size_t row = (size_t)(bm + wr * 128 + mi * 16 + er + r);
        size_t col = (size_t)(bn + wc * 64 + n * 16 + ec);
        C[row * N + col] = acc[mi][n][r];
      }
}

extern "C" void kernel_launch(void* const* d_in, const int* in_sizes, int n_in,
                              void* d_out, int out_size, void* d_ws,
                              size_t ws_size, hipStream_t stream) {
  const float* x = (const float*)d_in[0];   // (4,2048,2048)
  const float* W1 = (const float*)d_in[1];  // (8192,2048)
  const float* W2 = (const float*)d_in[2];  // (2048,8192)
  const float* W3 = (const float*)d_in[3];  // (8192,2048)
  float* out = (float*)d_out;

  const int M = 8192, D = 2048, H = 8192;
  const size_t NE = (size_t)16777216;

  unsigned short* xb = (unsigned short*)d_ws;
  unsigned short* w1b = xb + NE;
  unsigned short* w3b = w1b + NE;
  unsigned short* w2f = w3b + NE;
  unsigned short* hid = w2f + NE;  // M x H bf16

  conv_f32_bf16<<<2048, 256, 0, stream>>>(x, xb, (int)(NE / 4));
  conv_f32_bf16<<<2048, 256, 0, stream>>>(W1, w1b, (int)(NE / 4));
  conv_f32_bf16<<<2048, 256, 0, stream>>>(W3, w3b, (int)(NE / 4));
  fwht_rows_bf16<<<2048, 256, 0, stream>>>(W2, w2f);

  gemm1_dual_silu<<<(M / 256) * (H / 128), 512, 0, stream>>>(xb, w1b, w3b, hid,
                                                             M, H, D);
  gemm2_8ph<<<(M / 256) * (D / 256), 512, 0, stream>>>(hid, w2f, out, M, D, H);
}

// Round 3
// 836.925 us; speedup vs baseline: 1.2662x; 1.1386x over previous
//
#include <hip/hip_runtime.h>

typedef __attribute__((ext_vector_type(8))) __bf16 bf16x8;
typedef __attribute__((ext_vector_type(4))) float f32x4;

#define GLOAD_LDS16(g, l)                                                     \
  __builtin_amdgcn_global_load_lds(                                           \
      (const __attribute__((address_space(1))) void*)(g),                     \
      (__attribute__((address_space(3))) void*)(l), 16, 0, 0)

#define BAR() __builtin_amdgcn_s_barrier()
#define SB0() __builtin_amdgcn_sched_barrier(0)
#define LGKM(n)                                                               \
  do {                                                                        \
    asm volatile("s_waitcnt lgkmcnt(" #n ")" ::: "memory");                   \
    SB0();                                                                    \
  } while (0)
#define VMCNT0() asm volatile("s_waitcnt vmcnt(0)" ::: "memory")
#define PRIO1() __builtin_amdgcn_s_setprio(1)
#define PRIO0() __builtin_amdgcn_s_setprio(0)

__device__ __forceinline__ unsigned short f32_to_bf16(float f) {
  unsigned int u = __builtin_bit_cast(unsigned int, f);
  u += 0x7FFFu + ((u >> 16) & 1u);
  return (unsigned short)(u >> 16);
}

// ---------------- f32 -> bf16 conversion ----------------------------------
__global__ void conv_f32_bf16(const float* __restrict__ in,
                              unsigned short* __restrict__ out, int n4) {
  int stride = gridDim.x * blockDim.x;
  for (int i = blockIdx.x * blockDim.x + threadIdx.x; i < n4; i += stride) {
    float4 v = reinterpret_cast<const float4*>(in)[i];
    ushort4 o;
    o.x = f32_to_bf16(v.x);
    o.y = f32_to_bf16(v.y);
    o.z = f32_to_bf16(v.z);
    o.w = f32_to_bf16(v.w);
    reinterpret_cast<ushort4*>(out)[i] = o;
  }
}

// ---------------- FWHT rows of 8192, * 1/sqrt(8192), bf16 out --------------
__global__ void fwht_rows_bf16(const float* __restrict__ in,
                               unsigned short* __restrict__ out) {
  __shared__ float s[8192];
  const int tid = threadIdx.x;  // 256 threads
  const float* row = in + (size_t)blockIdx.x * 8192;
#pragma unroll
  for (int i = 0; i < 8; ++i)
    reinterpret_cast<float4*>(s)[tid + i * 256] =
        reinterpret_cast<const float4*>(row)[tid + i * 256];
  for (int h = 1; h < 8192; h <<= 1) {
    __syncthreads();
#pragma unroll
    for (int it = 0; it < 16; ++it) {
      int i = tid + it * 256;
      int j = ((i & ~(h - 1)) << 1) | (i & (h - 1));
      float a = s[j], b = s[j + h];
      s[j] = a + b;
      s[j + h] = a - b;
    }
  }
  __syncthreads();
  const float scale = 0.011048543456039806f;  // 1/sqrt(8192)
  unsigned short* orow = out + (size_t)blockIdx.x * 8192;
#pragma unroll
  for (int i = 0; i < 8; ++i) {
    float4 v = reinterpret_cast<const float4*>(s)[tid + i * 256];
    ushort4 o;
    o.x = f32_to_bf16(v.x * scale);
    o.y = f32_to_bf16(v.y * scale);
    o.z = f32_to_bf16(v.z * scale);
    o.w = f32_to_bf16(v.w * scale);
    reinterpret_cast<ushort4*>(orow)[tid + i * 256] = o;
  }
}

#define MFMA_BF16 __builtin_amdgcn_mfma_f32_16x16x32_bf16

// ======================= GEMM2: C(f32) = A · Bt^T ==========================
// tile 256x256, BK=64, 8 waves (2M x 4N), per-wave 128x64.
// One barrier + one vmcnt(0) per K-tile; reads+stages issued at tile head.
#define G2_TILE(BI, tt)                                                       \
  {                                                                           \
    _Pragma("unroll") for (int m = 0; m < 4; ++m) {                           \
      ra[m][0] = *(const bf16x8*)(Lb + ((BI)*32768 + m * 2048) + rA0);        \
      ra[m][1] = *(const bf16x8*)(Lb + ((BI)*32768 + m * 2048) + rA1);        \
    }                                                                         \
    _Pragma("unroll") for (int n = 0; n < 2; ++n) {                           \
      rb[n][0] = *(const bf16x8*)(Lb + ((BI)*32768 + n * 2048) + rB0);        \
      rb[n][1] = *(const bf16x8*)(Lb + ((BI)*32768 + n * 2048) + rB1);        \
    }                                                                         \
    SB0();                                                                    \
    _Pragma("unroll") for (int n = 2; n < 4; ++n) {                           \
      rb[n][0] = *(const bf16x8*)(Lb + ((BI)*32768 + n * 2048) + rB0);        \
      rb[n][1] = *(const bf16x8*)(Lb + ((BI)*32768 + n * 2048) + rB1);        \
    }                                                                         \
    SB0();                                                                    \
    if ((tt) + 1 < NT) {                                                      \
      unsigned short* dA = L + (((BI) ^ 1) * 16384) + wid * 512;              \
      unsigned short* dB = L + 32768 + (((BI) ^ 1) * 16384) + wid * 512;      \
      _Pragma("unroll") for (int i = 0; i < 4; ++i) {                         \
        GLOAD_LDS16(pA + i * s64, dA + i * 4096);                             \
        GLOAD_LDS16(pB + i * s64, dB + i * 4096);                             \
      }                                                                       \
    }                                                                         \
    SB0();                                                                    \
    LGKM(4);                                                                  \
    PRIO1();                                                                  \
    _Pragma("unroll") for (int m = 0; m < 4; ++m)                             \
        _Pragma("unroll") for (int n = 0; n < 2; ++n) {                       \
      acc[m][n] = MFMA_BF16(ra[m][0], rb[n][0], acc[m][n], 0, 0, 0);          \
      acc[m][n] = MFMA_BF16(ra[m][1], rb[n][1], acc[m][n], 0, 0, 0);          \
    }                                                                         \
    PRIO0();                                                                  \
    SB0();                                                                    \
    LGKM(0);                                                                  \
    PRIO1();                                                                  \
    _Pragma("unroll") for (int m = 0; m < 4; ++m)                             \
        _Pragma("unroll") for (int n = 2; n < 4; ++n) {                       \
      acc[m][n] = MFMA_BF16(ra[m][0], rb[n][0], acc[m][n], 0, 0, 0);          \
      acc[m][n] = MFMA_BF16(ra[m][1], rb[n][1], acc[m][n], 0, 0, 0);          \
    }                                                                         \
    PRIO0();                                                                  \
    SB0();                                                                    \
    _Pragma("unroll") for (int m = 0; m < 4; ++m) {                           \
      ra[m][0] = *(const bf16x8*)(Lb + ((BI)*32768 + (m + 4) * 2048) + rA0);  \
      ra[m][1] = *(const bf16x8*)(Lb + ((BI)*32768 + (m + 4) * 2048) + rA1);  \
    }                                                                         \
    SB0();                                                                    \
    LGKM(0);                                                                  \
    PRIO1();                                                                  \
    _Pragma("unroll") for (int m = 0; m < 4; ++m)                             \
        _Pragma("unroll") for (int n = 2; n < 4; ++n) {                       \
      acc[4 + m][n] = MFMA_BF16(ra[m][0], rb[n][0], acc[4 + m][n], 0, 0, 0);  \
      acc[4 + m][n] = MFMA_BF16(ra[m][1], rb[n][1], acc[4 + m][n], 0, 0, 0);  \
    }                                                                         \
    _Pragma("unroll") for (int m = 0; m < 4; ++m)                             \
        _Pragma("unroll") for (int n = 0; n < 2; ++n) {                       \
      acc[4 + m][n] = MFMA_BF16(ra[m][0], rb[n][0], acc[4 + m][n], 0, 0, 0);  \
      acc[4 + m][n] = MFMA_BF16(ra[m][1], rb[n][1], acc[4 + m][n], 0, 0, 0);  \
    }                                                                         \
    PRIO0();                                                                  \
    VMCNT0();                                                                 \
    BAR();                                                                    \
    pA += 128;                                                                \
    pB += 128;                                                                \
  }

__launch_bounds__(512, 2)
__global__ void gemm2_pipe(const unsigned short* __restrict__ A,
                           const unsigned short* __restrict__ Bt,
                           float* __restrict__ C, int M, int N, int K) {
  __shared__ __align__(16) unsigned short L[65536];  // A:[0,64KB) B:[64,128KB)
  const int tid = threadIdx.x, lane = tid & 63, wid = tid >> 6;
  const int wr = wid >> 2, wc = wid & 3;
  const int nbx = N >> 8;
  const int cpx = (int)gridDim.x >> 3;
  const int swz = ((int)blockIdx.x & 7) * cpx + ((int)blockIdx.x >> 3);
  const int bm = (swz / nbx) << 8, bn = (swz % nbx) << 8;
  const int NT = K >> 6;

  // per-lane LDS read offsets (swizzle folded): ks=0 / ks=1
  const int lp0 = (lane & 15) * 128 + (((lane >> 4) << 4) ^ ((lane & 7) << 4));
  const int lp1 =
      (lane & 15) * 128 + ((64 | ((lane >> 4) << 4)) ^ ((lane & 7) << 4));
  const int rA0 = wr * 16384 + lp0, rA1 = wr * 16384 + lp1;
  const int rB0 = 65536 + wc * 8192 + lp0, rB1 = 65536 + wc * 8192 + lp1;

  // per-lane global stage pointers (inverse swizzle folded into source col)
  const int swzc = ((lane & 7) ^ (lane >> 3)) << 4;
  const char* pA = (const char*)A +
                   ((size_t)(bm + (wid << 3) + (lane >> 3)) * K) * 2 + swzc;
  const char* pB = (const char*)Bt +
                   ((size_t)(bn + (wid << 3) + (lane >> 3)) * K) * 2 + swzc;
  const size_t s64 = (size_t)K * 128;  // 64 rows stride (bytes)
  const char* Lb = (const char*)L;

  {  // prologue: stage tile 0 into buf0
    unsigned short* dA = L + wid * 512;
    unsigned short* dB = L + 32768 + wid * 512;
#pragma unroll
    for (int i = 0; i < 4; ++i) {
      GLOAD_LDS16(pA + i * s64, dA + i * 4096);
      GLOAD_LDS16(pB + i * s64, dB + i * 4096);
    }
  }
  pA += 128;
  pB += 128;

  f32x4 acc[8][4];
#pragma unroll
  for (int m = 0; m < 8; ++m)
#pragma unroll
    for (int n = 0; n < 4; ++n) acc[m][n] = (f32x4)0.0f;
  bf16x8 ra[4][2], rb[4][2];

  VMCNT0();
  BAR();

  for (int t = 0; t < NT; t += 2) {
    G2_TILE(0, t)
    G2_TILE(1, t + 1)
  }

  const int er = (lane >> 4) << 2;
  const int ec = lane & 15;
#pragma unroll
  for (int mi = 0; mi < 8; ++mi)
#pragma unroll
    for (int n = 0; n < 4; ++n)
#pragma unroll
      for (int r = 0; r < 4; ++r) {
        size_t row = (size_t)(bm + wr * 128 + mi * 16 + er + r);
        size_t col = (size_t)(bn + wc * 64 + n * 16 + ec);
        C[row * N + col] = acc[mi][n][r];
      }
}

// ======================= GEMM1: dual-B + silu fuse =========================
// tile 256x128, BK=64, 8 waves (4M x 2N), per-wave 64x64, dual accum.
// LDS carve (ushorts): A [0,32768), B1 [32768,49152), B3 [49152,65536).
#define G1_TILE(BI, tt)                                                       \
  {                                                                           \
    _Pragma("unroll") for (int m = 0; m < 4; ++m) {                           \
      ra[m][0] = *(const bf16x8*)(Lb + ((BI)*32768 + m * 2048) + rA0);        \
      ra[m][1] = *(const bf16x8*)(Lb + ((BI)*32768 + m * 2048) + rA1);        \
    }                                                                         \
    _Pragma("unroll") for (int n = 0; n < 2; ++n) {                           \
      rb[n][0] = *(const bf16x8*)(Lb + ((BI)*16384 + n * 2048) + rB0);        \
      rb[n][1] = *(const bf16x8*)(Lb + ((BI)*16384 + n * 2048) + rB1);        \
    }                                                                         \
    SB0();                                                                    \
    _Pragma("unroll") for (int n = 2; n < 4; ++n) {                           \
      rb[n][0] = *(const bf16x8*)(Lb + ((BI)*16384 + n * 2048) + rB0);        \
      rb[n][1] = *(const bf16x8*)(Lb + ((BI)*16384 + n * 2048) + rB1);        \
    }                                                                         \
    SB0();                                                                    \
    if ((tt) + 1 < NT) {                                                      \
      unsigned short* dA = L + (((BI) ^ 1) * 16384) + wid * 512;              \
      unsigned short* dB1 = L + 32768 + (((BI) ^ 1) * 8192) + wid * 512;      \
      unsigned short* dB3 = L + 49152 + (((BI) ^ 1) * 8192) + wid * 512;      \
      _Pragma("unroll") for (int i = 0; i < 4; ++i)                           \
          GLOAD_LDS16(pA + i * s64, dA + i * 4096);                           \
      _Pragma("unroll") for (int i = 0; i < 2; ++i) {                         \
        GLOAD_LDS16(pB1 + i * s64, dB1 + i * 4096);                           \
        GLOAD_LDS16(pB3 + i * s64, dB3 + i * 4096);                           \
      }                                                                       \
    }                                                                         \
    SB0();                                                                    \
    LGKM(4);                                                                  \
    PRIO1();                                                                  \
    _Pragma("unroll") for (int m = 0; m < 4; ++m)                             \
        _Pragma("unroll") for (int n = 0; n < 2; ++n) {                       \
      accG[m][n] = MFMA_BF16(ra[m][0], rb[n][0], accG[m][n], 0, 0, 0);        \
      accG[m][n] = MFMA_BF16(ra[m][1], rb[n][1], accG[m][n], 0, 0, 0);        \
    }                                                                         \
    PRIO0();                                                                  \
    SB0();                                                                    \
    LGKM(0);                                                                  \
    PRIO1();                                                                  \
    _Pragma("unroll") for (int m = 0; m < 4; ++m)                             \
        _Pragma("unroll") for (int n = 2; n < 4; ++n) {                       \
      accG[m][n] = MFMA_BF16(ra[m][0], rb[n][0], accG[m][n], 0, 0, 0);        \
      accG[m][n] = MFMA_BF16(ra[m][1], rb[n][1], accG[m][n], 0, 0, 0);        \
    }                                                                         \
    PRIO0();                                                                  \
    SB0();                                                                    \
    _Pragma("unroll") for (int n = 2; n < 4; ++n) { /* B3 n2,3 first */       \
      rb[n][0] = *(const bf16x8*)(Lb + (32768 + (BI)*16384 + n * 2048) + rB0);\
      rb[n][1] = *(const bf16x8*)(Lb + (32768 + (BI)*16384 + n * 2048) + rB1);\
    }                                                                         \
    SB0();                                                                    \
    _Pragma("unroll") for (int n = 0; n < 2; ++n) {                           \
      rb[n][0] = *(const bf16x8*)(Lb + (32768 + (BI)*16384 + n * 2048) + rB0);\
      rb[n][1] = *(const bf16x8*)(Lb + (32768 + (BI)*16384 + n * 2048) + rB1);\
    }                                                                         \
    SB0();                                                                    \
    LGKM(4);                                                                  \
    PRIO1();                                                                  \
    _Pragma("unroll") for (int m = 0; m < 4; ++m)                             \
        _Pragma("unroll") for (int n = 2; n < 4; ++n) {                       \
      accL[m][n] = MFMA_BF16(ra[m][0], rb[n][0], accL[m][n], 0, 0, 0);        \
      accL[m][n] = MFMA_BF16(ra[m][1], rb[n][1], accL[m][n], 0, 0, 0);        \
    }                                                                         \
    PRIO0();                                                                  \
    SB0();                                                                    \
    LGKM(0);                                                                  \
    PRIO1();                                                                  \
    _Pragma("unroll") for (int m = 0; m < 4; ++m)                             \
        _Pragma("unroll") for (int n = 0; n < 2; ++n) {                       \
      accL[m][n] = MFMA_BF16(ra[m][0], rb[n][0], accL[m][n], 0, 0, 0);        \
      accL[m][n] = MFMA_BF16(ra[m][1], rb[n][1], accL[m][n], 0, 0, 0);        \
    }                                                                         \
    PRIO0();                                                                  \
    VMCNT0();                                                                 \
    BAR();                                                                    \
    pA += 128;                                                                \
    pB1 += 128;                                                               \
    pB3 += 128;                                                               \
  }

__launch_bounds__(512, 2)
__global__ void gemm1_pipe(const unsigned short* __restrict__ A,
                           const unsigned short* __restrict__ B1p,
                           const unsigned short* __restrict__ B3p,
                           unsigned short* __restrict__ Hout, int M, int N,
                           int K) {
  __shared__ __align__(16) unsigned short L[65536];
  const int tid = threadIdx.x, lane = tid & 63, wid = tid >> 6;
  const int wr = wid >> 1, wc = wid & 1;
  const int nby = M >> 8;  // 32
  const int cpx = (int)gridDim.x >> 3;
  const int swz = ((int)blockIdx.x & 7) * cpx + ((int)blockIdx.x >> 3);
  const int bm = (swz % nby) << 8;
  const int bn = (swz / nby) << 7;
  const int NT = K >> 6;

  const int lp0 = (lane & 15) * 128 + (((lane >> 4) << 4) ^ ((lane & 7) << 4));
  const int lp1 =
      (lane & 15) * 128 + ((64 | ((lane >> 4) << 4)) ^ ((lane & 7) << 4));
  const int rA0 = wr * 8192 + lp0, rA1 = wr * 8192 + lp1;
  const int rB0 = 65536 + wc * 8192 + lp0, rB1 = 65536 + wc * 8192 + lp1;

  const int swzc = ((lane & 7) ^ (lane >> 3)) << 4;
  const char* pA = (const char*)A +
                   ((size_t)(bm + (wid << 3) + (lane >> 3)) * K) * 2 + swzc;
  const char* pB1 = (const char*)B1p +
                    ((size_t)(bn + (wid << 3) + (lane >> 3)) * K) * 2 + swzc;
  const char* pB3 = (const char*)B3p +
                    ((size_t)(bn + (wid << 3) + (lane >> 3)) * K) * 2 + swzc;
  const size_t s64 = (size_t)K * 128;
  const char* Lb = (const char*)L;

  {  // prologue
    unsigned short* dA = L + wid * 512;
    unsigned short* dB1 = L + 32768 + wid * 512;
    unsigned short* dB3 = L + 49152 + wid * 512;
#pragma unroll
    for (int i = 0; i < 4; ++i) GLOAD_LDS16(pA + i * s64, dA + i * 4096);
#pragma unroll
    for (int i = 0; i < 2; ++i) {
      GLOAD_LDS16(pB1 + i * s64, dB1 + i * 4096);
      GLOAD_LDS16(pB3 + i * s64, dB3 + i * 4096);
    }
  }
  pA += 128;
  pB1 += 128;
  pB3 += 128;

  f32x4 accG[4][4], accL[4][4];
#pragma unroll
  for (int m = 0; m < 4; ++m)
#pragma unroll
    for (int n = 0; n < 4; ++n) {
      accG[m][n] = (f32x4)0.0f;
      accL[m][n] = (f32x4)0.0f;
    }
  bf16x8 ra[4][2], rb[4][2];

  VMCNT0();
  BAR();

  for (int t = 0; t < NT; t += 2) {
    G1_TILE(0, t)
    G1_TILE(1, t + 1)
  }

  const int er = (lane >> 4) << 2;
  const int ec = lane & 15;
#pragma unroll
  for (int m = 0; m < 4; ++m)
#pragma unroll
    for (int n = 0; n < 4; ++n)
#pragma unroll
      for (int r = 0; r < 4; ++r) {
        float g = accG[m][n][r];
        float li = accL[m][n][r];
        float h = (g / (1.0f + __expf(-g))) * li;
        size_t row = (size_t)(bm + wr * 64 + m * 16 + er + r);
        size_t col = (size_t)(bn + wc * 64 + n * 16 + ec);
        Hout[row * N + col] = f32_to_bf16(h);
      }
}

extern "C" void kernel_launch(void* const* d_in, const int* in_sizes, int n_in,
                              void* d_out, int out_size, void* d_ws,
                              size_t ws_size, hipStream_t stream) {
  const float* x = (const float*)d_in[0];   // (4,2048,2048)
  const float* W1 = (const float*)d_in[1];  // (8192,2048)
  const float* W2 = (const float*)d_in[2];  // (2048,8192)
  const float* W3 = (const float*)d_in[3];  // (8192,2048)
  float* out = (float*)d_out;

  const int M = 8192, D = 2048, H = 8192;
  const size_t NE = (size_t)16777216;

  unsigned short* xb = (unsigned short*)d_ws;
  unsigned short* w1b = xb + NE;
  unsigned short* w3b = w1b + NE;
  unsigned short* w2f = w3b + NE;
  unsigned short* hid = w2f + NE;  // M x H bf16

  conv_f32_bf16<<<2048, 256, 0, stream>>>(x, xb, (int)(NE / 4));
  conv_f32_bf16<<<2048, 256, 0, stream>>>(W1, w1b, (int)(NE / 4));
  conv_f32_bf16<<<2048, 256, 0, stream>>>(W3, w3b, (int)(NE / 4));
  fwht_rows_bf16<<<2048, 256, 0, stream>>>(W2, w2f);

  gemm1_pipe<<<(M / 256) * (H / 128), 512, 0, stream>>>(xb, w1b, w3b, hid, M,
                                                        H, D);
  gemm2_pipe<<<(M / 256) * (D / 256), 512, 0, stream>>>(hid, w2f, out, M, D,
                                                        H);
}